// Round 1
// baseline (29.901 us; speedup 1.0000x reference)
//
#include <hip/hip_runtime.h>

#define BATCH 4
#define HH 128
#define WW 128
#define CC 64
#define PADR 2
#define NK 25          // 5x5 window slots
#define TH 8
#define TW 8
#define HALO 12        // TH + 4
#define HPOS 144       // 12*12
#define LSTRIDE 68     // 64 + 4 pad floats (272 B, 16B aligned, stride%32==4)

__global__ __launch_bounds__(256) void local_attn_kernel(
    const float* __restrict__ main_,
    const float* __restrict__ main_value,
    const float* __restrict__ ref,
    const float* __restrict__ ref_value,
    float* __restrict__ out)
{
    __shared__ float buf[HPOS * LSTRIDE];   // 39168 B, restaged between phases

    const int t    = threadIdx.x;
    const int blk  = blockIdx.x;            // b*256 + by*16 + bx
    const int bx   = blk & 15;
    const int by   = (blk >> 4) & 15;
    const int b    = blk >> 8;

    const int lane = t & 63;
    const int wave = t >> 6;
    const int pxl  = lane >> 2;             // 0..15 : pixel within wave
    const int cg   = lane & 3;              // channel quarter
    const int ly   = wave * 2 + (pxl >> 3); // 0..7
    const int lx   = pxl & 7;               // 0..7
    const int gy   = by * TH + ly;
    const int gx   = bx * TW + lx;

    const size_t img_base = (size_t)b * HH * WW * CC;
    const size_t px_off   = img_base + ((size_t)gy * WW + gx) * CC + cg * 16;

    const int y0 = by * TH - PADR;
    const int x0 = bx * TW - PADR;

    // ---- stage ref halo (12x12 x 64ch) ----
    {
        const int c4 = t & 15;              // which float4 of the 64-ch row
        int pos = t >> 4;
        #pragma unroll
        for (int it = 0; it < 9; ++it, pos += 16) {
            int hy = pos / 12, hx = pos - hy * 12;
            int yy = y0 + hy, xx = x0 + hx;
            float4 v = make_float4(0.f, 0.f, 0.f, 0.f);
            if ((unsigned)yy < HH && (unsigned)xx < WW)
                v = *(const float4*)(ref + img_base + ((size_t)yy * WW + xx) * CC + c4 * 4);
            *(float4*)(buf + pos * LSTRIDE + c4 * 4) = v;
        }
    }

    // ---- load q (my 16 channels) ----
    float q[16];
    #pragma unroll
    for (int i = 0; i < 4; ++i) {
        float4 v = *(const float4*)(main_ + px_off + i * 4);
        q[i*4+0] = v.x; q[i*4+1] = v.y; q[i*4+2] = v.z; q[i*4+3] = v.w;
    }

    __syncthreads();

    // ---- attention logits: 25 window dots + self dot ----
    float p[26];
    #pragma unroll
    for (int k = 0; k < NK; ++k) {
        const int di = k / 5, dj = k % 5;
        const float* base = buf + ((ly + di) * 12 + (lx + dj)) * LSTRIDE + cg * 16;
        float acc = 0.f;
        #pragma unroll
        for (int i = 0; i < 4; ++i) {
            float4 v = *(const float4*)(base + i * 4);
            acc += q[i*4+0]*v.x + q[i*4+1]*v.y + q[i*4+2]*v.z + q[i*4+3]*v.w;
        }
        // reduce over the 4 channel-quarter lanes
        acc += __shfl_xor(acc, 1);
        acc += __shfl_xor(acc, 2);
        p[k] = acc;
    }
    {
        float acc = 0.f;
        #pragma unroll
        for (int c = 0; c < 16; ++c) acc += q[c] * q[c];
        acc += __shfl_xor(acc, 1);
        acc += __shfl_xor(acc, 2);
        p[25] = acc;
    }

    // ---- softmax (deferred normalization) ----
    float m = p[0];
    #pragma unroll
    for (int k = 1; k < 26; ++k) m = fmaxf(m, p[k]);
    float s = 0.f;
    #pragma unroll
    for (int k = 0; k < 26; ++k) { p[k] = __expf(p[k] - m); s += p[k]; }
    const float rs = 1.f / s;

    __syncthreads();

    // ---- restage LDS with ref_value halo ----
    {
        const int c4 = t & 15;
        int pos = t >> 4;
        #pragma unroll
        for (int it = 0; it < 9; ++it, pos += 16) {
            int hy = pos / 12, hx = pos - hy * 12;
            int yy = y0 + hy, xx = x0 + hx;
            float4 v = make_float4(0.f, 0.f, 0.f, 0.f);
            if ((unsigned)yy < HH && (unsigned)xx < WW)
                v = *(const float4*)(ref_value + img_base + ((size_t)yy * WW + xx) * CC + c4 * 4);
            *(float4*)(buf + pos * LSTRIDE + c4 * 4) = v;
        }
    }
    __syncthreads();

    // ---- aggregation: out[c] = sum_k p_k * value_k[c] (my 16 bins) ----
    float acc[16];
    #pragma unroll
    for (int c = 0; c < 16; ++c) acc[c] = 0.f;

    #pragma unroll
    for (int k = 0; k < NK; ++k) {
        const int di = k / 5, dj = k % 5;
        const float* base = buf + ((ly + di) * 12 + (lx + dj)) * LSTRIDE + cg * 16;
        const float pk = p[k];
        #pragma unroll
        for (int i = 0; i < 4; ++i) {
            float4 v = *(const float4*)(base + i * 4);
            acc[i*4+0] += pk * v.x; acc[i*4+1] += pk * v.y;
            acc[i*4+2] += pk * v.z; acc[i*4+3] += pk * v.w;
        }
    }
    {   // self slot: main_value
        const float pk = p[25];
        #pragma unroll
        for (int i = 0; i < 4; ++i) {
            float4 v = *(const float4*)(main_value + px_off + i * 4);
            acc[i*4+0] += pk * v.x; acc[i*4+1] += pk * v.y;
            acc[i*4+2] += pk * v.z; acc[i*4+3] += pk * v.w;
        }
    }

    #pragma unroll
    for (int i = 0; i < 4; ++i) {
        float4 v = make_float4(acc[i*4+0]*rs, acc[i*4+1]*rs,
                               acc[i*4+2]*rs, acc[i*4+3]*rs);
        *(float4*)(out + px_off + i * 4) = v;
    }
}

extern "C" void kernel_launch(void* const* d_in, const int* in_sizes, int n_in,
                              void* d_out, int out_size, void* d_ws, size_t ws_size,
                              hipStream_t stream) {
    const float* main_      = (const float*)d_in[0];
    const float* main_value = (const float*)d_in[1];
    const float* ref        = (const float*)d_in[2];
    const float* ref_value  = (const float*)d_in[3];
    float* out = (float*)d_out;

    // grid: 4 batches * 16x16 tiles of 8x8 pixels
    local_attn_kernel<<<dim3(BATCH * 16 * 16), dim3(256), 0, stream>>>(
        main_, main_value, ref, ref_value, out);
}